// Round 9
// baseline (194.156 us; speedup 1.0000x reference)
//
#include <hip/hip_runtime.h>
#include <hip/hip_bf16.h>
#include <math.h>

#define B_ 4
#define T_ 4096
#define C_ 384
#define H_ 64
#define KVB 64
#define NSPL 4

typedef __attribute__((ext_vector_type(8))) short bf16x8;
typedef __attribute__((ext_vector_type(4))) float f32x4;

static __device__ __forceinline__ short f2bf(float f) {
  return (short)(((__hip_bfloat16_raw)__float2bfloat16(f)).x);
}

// ---------------- W convert+transpose: Wt[w3][h][c] bf16 ---------------------
__global__ __launch_bounds__(256) void wconv_kernel(
    const float* __restrict__ Wk, const float* __restrict__ Wq,
    const float* __restrict__ Wv, short* __restrict__ Wt)
{
  const int w3 = blockIdx.y;
  const float* W = (w3 == 0) ? Wk : (w3 == 1) ? Wq : Wv;
  const int i = blockIdx.x * 256 + threadIdx.x;   // i = h*C_ + c
  const int h = i / C_;
  const int c = i - h * C_;
  Wt[w3 * (H_ * C_) + i] = f2bf(W[c * H_ + h]);
}

// ---------------- Projection: grid (256,3), wave = 16 rows x 64 cols ---------
// w3==2 uses swapped operands to emit V^T directly (coalesced stores).
__global__ __launch_bounds__(256, 3) void proj_mfma(
    const float* __restrict__ x, const short* __restrict__ Wt,
    short* __restrict__ qb, short* __restrict__ kb, short* __restrict__ vbT)
{
  const int tid = threadIdx.x;
  const int wave = tid >> 6, lane = tid & 63;
  const int lrow = lane & 15, lgrp = lane >> 4;
  const int row0 = blockIdx.x * 64 + wave * 16;
  const int w3 = blockIdx.y;

  // x A-fragments (also valid as B-fragments: identical lane->element map)
  bf16x8 af[12];
  #pragma unroll
  for (int ks = 0; ks < 12; ++ks) {
    const float* gp = x + (size_t)(row0 + lrow) * C_ + ks * 32 + lgrp * 8;
    const float4 f0 = *(const float4*)gp;
    const float4 f1 = *(const float4*)(gp + 4);
    bf16x8 bv;
    bv[0] = f2bf(f0.x); bv[1] = f2bf(f0.y); bv[2] = f2bf(f0.z); bv[3] = f2bf(f0.w);
    bv[4] = f2bf(f1.x); bv[5] = f2bf(f1.y); bv[6] = f2bf(f1.z); bv[7] = f2bf(f1.w);
    af[ks] = bv;
  }

  const short* Wp = Wt + w3 * (H_ * C_);

  if (w3 == 2) {
    // V^T: acc = Wv^T(16 h-rows) x x^T(16 t-cols); D row=h, col=t
    const int bb = row0 >> 12;
    const int tt = row0 & (T_ - 1);
    #pragma unroll
    for (int n = 0; n < 4; ++n) {
      bf16x8 wf[12];
      #pragma unroll
      for (int ks = 0; ks < 12; ++ks)
        wf[ks] = *(const bf16x8*)(Wp + (n * 16 + lrow) * C_ + ks * 32 + lgrp * 8);
      f32x4 acc = {0.f, 0.f, 0.f, 0.f};
      #pragma unroll
      for (int ks = 0; ks < 12; ++ks)
        acc = __builtin_amdgcn_mfma_f32_16x16x32_bf16(wf[ks], af[ks], acc, 0, 0, 0);
      #pragma unroll
      for (int r = 0; r < 4; ++r)
        vbT[(size_t)(bb * H_ + n * 16 + lgrp * 4 + r) * T_ + tt + lrow] = f2bf(acc[r]);
    }
  } else {
    short* outp = (w3 == 0) ? kb : qb;
    #pragma unroll
    for (int n = 0; n < 4; ++n) {
      bf16x8 wf[12];
      #pragma unroll
      for (int ks = 0; ks < 12; ++ks)
        wf[ks] = *(const bf16x8*)(Wp + (n * 16 + lrow) * C_ + ks * 32 + lgrp * 8);
      f32x4 acc = {0.f, 0.f, 0.f, 0.f};
      #pragma unroll
      for (int ks = 0; ks < 12; ++ks)
        acc = __builtin_amdgcn_mfma_f32_16x16x32_bf16(af[ks], wf[ks], acc, 0, 0, 0);
      #pragma unroll
      for (int r = 0; r < 4; ++r)
        outp[(size_t)(row0 + lgrp * 4 + r) * H_ + n * 16 + lrow] = f2bf(acc[r]);
    }
  }
}

// ---------------- Flash attention: barrier-free independent waves ------------
// One wave per (16-row q-tile, KV-split). K/V fragments loaded straight from
// global (L2/L3-resident); LDS only for the per-wave P transpose (2 KB).
__global__ __launch_bounds__(256, 4) void attn_kernel(
    const short* __restrict__ qb, const short* __restrict__ kb,
    const short* __restrict__ vbT, float* __restrict__ po,
    float* __restrict__ pm, float* __restrict__ pl)
{
  __shared__ __align__(16) char lds_all[4 * 2048];
  const int tid = threadIdx.x;
  const int ws = tid >> 6;                        // wave id == KV-split id
  const int lane = tid & 63;
  const int lrow = lane & 15, lgrp = lane >> 4;
  const int swzA = (lrow & 7) << 4;
  char* lds_p = lds_all + ws * 2048;

  const int qi = (T_ / 16 - 1) - (blockIdx.x >> 2);  // longest tasks first
  const int b  = blockIdx.x & 3;
  const int qrow0 = qi * 16;

  const short* Q  = qb  + (size_t)b * T_ * H_;
  const short* K  = kb  + (size_t)b * T_ * H_;
  const short* Vt = vbT + (size_t)b * H_ * T_;

  const bf16x8 qf0 = *(const bf16x8*)(Q + (size_t)(qrow0 + lrow) * H_ + lgrp * 8);
  const bf16x8 qf1 = *(const bf16x8*)(Q + (size_t)(qrow0 + lrow) * H_ + 32 + lgrp * 8);

  f32x4 o[4];
  float m[4], l[4];
  #pragma unroll
  for (int n = 0; n < 4; ++n) o[n] = f32x4{0.f, 0.f, 0.f, 0.f};
  #pragma unroll
  for (int r = 0; r < 4; ++r) { m[r] = -INFINITY; l[r] = 0.f; }

  const float sc = 0.05103103630798288f;          // 384^-0.5
  const int nch = (qrow0 + 16 + KVB - 1) / KVB;   // causal chunk count

  for (int c4 = ws; c4 < nch; c4 += NSPL) {
    const int kv0 = c4 * KVB;

    // ---- K fragments straight from global (B-frag: 8 contiguous h) ----
    bf16x8 kf0[4], kf1[4];
    #pragma unroll
    for (int t4 = 0; t4 < 4; ++t4) {
      const short* kp = K + (size_t)(kv0 + t4 * 16 + lrow) * H_ + lgrp * 8;
      kf0[t4] = *(const bf16x8*)(kp);
      kf1[t4] = *(const bf16x8*)(kp + 32);
    }

    // ---- S = Q K^T ----
    f32x4 s[4];
    #pragma unroll
    for (int t4 = 0; t4 < 4; ++t4) {
      s[t4] = __builtin_amdgcn_mfma_f32_16x16x32_bf16(qf0, kf0[t4],
                  f32x4{0.f, 0.f, 0.f, 0.f}, 0, 0, 0);
      s[t4] = __builtin_amdgcn_mfma_f32_16x16x32_bf16(qf1, kf1[t4], s[t4], 0, 0, 0);
    }

    // ---- V fragments issue now (independent of s; latency hides under
    //      softmax).  B-frag from vbT: 8 contiguous t at row h. ----
    bf16x8 vf0[4], vf1[4];
    #pragma unroll
    for (int n = 0; n < 4; ++n) {
      const short* vp = Vt + (size_t)(n * 16 + lrow) * T_ + kv0 + lgrp * 8;
      vf0[n] = *(const bf16x8*)(vp);
      vf1[n] = *(const bf16x8*)(vp + 32);
    }

    // ---- scale; mask on any chunk reaching past the wave's first row ----
    if (kv0 + KVB > qrow0) {
      #pragma unroll
      for (int t4 = 0; t4 < 4; ++t4)
        #pragma unroll
        for (int r = 0; r < 4; ++r) {
          const int rg = qrow0 + lgrp * 4 + r;
          const int col = kv0 + t4 * 16 + lrow;
          s[t4][r] = (col > rg) ? -INFINITY : s[t4][r] * sc;
        }
    } else {
      #pragma unroll
      for (int t4 = 0; t4 < 4; ++t4)
        #pragma unroll
        for (int r = 0; r < 4; ++r) s[t4][r] *= sc;
    }

    // ---- online softmax (row reduce across the 16 kv-col lanes) ----
    float cm[4], cs[4];
    #pragma unroll
    for (int r = 0; r < 4; ++r)
      cm[r] = fmaxf(fmaxf(s[0][r], s[1][r]), fmaxf(s[2][r], s[3][r]));
    #pragma unroll
    for (int d = 1; d < 16; d <<= 1)
      #pragma unroll
      for (int r = 0; r < 4; ++r) cm[r] = fmaxf(cm[r], __shfl_xor(cm[r], d, 64));
    #pragma unroll
    for (int r = 0; r < 4; ++r) {
      const float nm = fmaxf(m[r], cm[r]);
      const float alpha = __expf(m[r] - nm);
      m[r] = nm;
      #pragma unroll
      for (int t4 = 0; t4 < 4; ++t4) s[t4][r] = __expf(s[t4][r] - nm);
      cs[r] = (s[0][r] + s[1][r]) + (s[2][r] + s[3][r]);
      #pragma unroll
      for (int n = 0; n < 4; ++n) o[n][r] *= alpha;
      l[r] *= alpha;
    }
    #pragma unroll
    for (int d = 1; d < 16; d <<= 1)
      #pragma unroll
      for (int r = 0; r < 4; ++r) cs[r] += __shfl_xor(cs[r], d, 64);
    #pragma unroll
    for (int r = 0; r < 4; ++r) l[r] += cs[r];

    // ---- P (C-layout) -> per-wave LDS -> A-frags (same-wave: lgkmcnt only) --
    #pragma unroll
    for (int t4 = 0; t4 < 4; ++t4)
      #pragma unroll
      for (int r = 0; r < 4; ++r) {
        const int row = lgrp * 4 + r;
        *(short*)(lds_p + ((row * 128 + (t4 * 16 + lrow) * 2) ^ ((row & 7) << 4))) =
            f2bf(s[t4][r]);
      }
    const bf16x8 pf0 = *(const bf16x8*)(lds_p + ((lrow * 128 + lgrp * 16) ^ swzA));
    const bf16x8 pf1 = *(const bf16x8*)(lds_p + ((lrow * 128 + 64 + lgrp * 16) ^ swzA));

    // ---- O += P V ----
    #pragma unroll
    for (int n = 0; n < 4; ++n) {
      o[n] = __builtin_amdgcn_mfma_f32_16x16x32_bf16(pf0, vf0[n], o[n], 0, 0, 0);
      o[n] = __builtin_amdgcn_mfma_f32_16x16x32_bf16(pf1, vf1[n], o[n], 0, 0, 0);
    }
  }

  // ---- write partials (unnormalized o, m, l) ----
  const size_t rowg = (size_t)b * T_ + qrow0;
  float* pob = po + (size_t)ws * (B_ * T_ * H_);
  #pragma unroll
  for (int n = 0; n < 4; ++n)
    #pragma unroll
    for (int r = 0; r < 4; ++r)
      pob[(rowg + lgrp * 4 + r) * H_ + n * 16 + lrow] = o[n][r];
  if (lrow == 0) {
    #pragma unroll
    for (int r = 0; r < 4; ++r) {
      pm[(size_t)ws * (B_ * T_) + rowg + lgrp * 4 + r] = m[r];
      pl[(size_t)ws * (B_ * T_) + rowg + lgrp * 4 + r] = l[r];
    }
  }
}

// ---------------- Merge the NSPL split partials ------------------------------
__global__ __launch_bounds__(256) void merge_kernel(
    const float* __restrict__ po, const float* __restrict__ pm,
    const float* __restrict__ pl, float* __restrict__ out)
{
  const int idx = blockIdx.x * 256 + threadIdx.x; // 0 .. B*T*H-1
  const int row = idx >> 6;
  float ms[NSPL], M = -INFINITY;
  #pragma unroll
  for (int s = 0; s < NSPL; ++s) {
    ms[s] = pm[(size_t)s * (B_ * T_) + row];
    M = fmaxf(M, ms[s]);
  }
  float num = 0.f, den = 0.f;
  #pragma unroll
  for (int s = 0; s < NSPL; ++s) {
    const float w = __expf(ms[s] - M);            // 0 for idle splits
    num += w * po[(size_t)s * (B_ * T_ * H_) + idx];
    den += w * pl[(size_t)s * (B_ * T_) + row];
  }
  out[idx] = num / den;
}

extern "C" void kernel_launch(void* const* d_in, const int* in_sizes, int n_in,
                              void* d_out, int out_size, void* d_ws, size_t ws_size,
                              hipStream_t stream) {
  const float* x  = (const float*)d_in[0];
  const float* Wk = (const float*)d_in[1];
  const float* Wq = (const float*)d_in[2];
  const float* Wv = (const float*)d_in[3];
  float* out = (float*)d_out;

  const size_t ntok = (size_t)B_ * T_;            // 16384
  char* ws = (char*)d_ws;
  short* qb  = (short*)ws;                                  // 2 MB
  short* kb  = qb + ntok * H_;                              // 2 MB
  short* vbT = kb + ntok * H_;                              // 2 MB
  short* Wt  = vbT + ntok * H_;                             // 144 KB
  float* po  = (float*)(ws + 3 * ntok * H_ * 2 + 3 * H_ * C_ * 2);  // 16 MB
  float* pm  = po + (size_t)NSPL * ntok * H_;               // 256 KB
  float* pl  = pm + (size_t)NSPL * ntok;                    // 256 KB

  wconv_kernel<<<dim3(96, 3), 256, 0, stream>>>(Wk, Wq, Wv, Wt);
  proj_mfma<<<dim3((int)(ntok / 64), 3), 256, 0, stream>>>(x, Wt, qb, kb, vbT);
  attn_kernel<<<(T_ / 16) * B_, 256, 0, stream>>>(qb, kb, vbT, po, pm, pl);
  merge_kernel<<<(int)(ntok * H_ / 256), 256, 0, stream>>>(po, pm, pl, out);
}

// Round 13
// 139.166 us; speedup vs baseline: 1.3951x; 1.3951x over previous
//
#include <hip/hip_runtime.h>
#include <hip/hip_bf16.h>
#include <math.h>

#define B_ 4
#define T_ 4096
#define C_ 384
#define H_ 64
#define NSPL 4

typedef __attribute__((ext_vector_type(8))) short bf16x8;
typedef __attribute__((ext_vector_type(4))) float f32x4;
typedef __attribute__((ext_vector_type(16))) float f32x16;
typedef __attribute__((ext_vector_type(4))) unsigned int u32x4;

static __device__ __forceinline__ short f2bf(float f) {
  return (short)(((__hip_bfloat16_raw)__float2bfloat16(f)).x);
}
static __device__ __forceinline__ unsigned cvtpk(float lo, float hi) {
  unsigned r;
  asm("v_cvt_pk_bf16_f32 %0, %1, %2" : "=v"(r) : "v"(lo), "v"(hi));
  return r;
}

// ---------------- W convert+transpose: Wt[w3][h][c] bf16 ---------------------
__global__ __launch_bounds__(256) void wconv_kernel(
    const float* __restrict__ Wk, const float* __restrict__ Wq,
    const float* __restrict__ Wv, short* __restrict__ Wt)
{
  const int w3 = blockIdx.y;
  const float* W = (w3 == 0) ? Wk : (w3 == 1) ? Wq : Wv;
  const int i = blockIdx.x * 256 + threadIdx.x;   // i = h*C_ + c
  const int h = i / C_;
  const int c = i - h * C_;
  Wt[w3 * (H_ * C_) + i] = f2bf(W[c * H_ + h]);
}

// ---------------- Projection: grid (256,3), wave = 16 rows x 64 cols ---------
// w3==2 emits V^T directly; w3==1 (q) folds the 384^-0.5 softmax scale in.
__global__ __launch_bounds__(256, 3) void proj_mfma(
    const float* __restrict__ x, const short* __restrict__ Wt,
    short* __restrict__ qb, short* __restrict__ kb, short* __restrict__ vbT)
{
  const int tid = threadIdx.x;
  const int wave = tid >> 6, lane = tid & 63;
  const int lrow = lane & 15, lgrp = lane >> 4;
  const int row0 = blockIdx.x * 64 + wave * 16;
  const int w3 = blockIdx.y;

  bf16x8 af[12];
  #pragma unroll
  for (int ks = 0; ks < 12; ++ks) {
    const float* gp = x + (size_t)(row0 + lrow) * C_ + ks * 32 + lgrp * 8;
    const float4 f0 = *(const float4*)gp;
    const float4 f1 = *(const float4*)(gp + 4);
    bf16x8 bv;
    bv[0] = f2bf(f0.x); bv[1] = f2bf(f0.y); bv[2] = f2bf(f0.z); bv[3] = f2bf(f0.w);
    bv[4] = f2bf(f1.x); bv[5] = f2bf(f1.y); bv[6] = f2bf(f1.z); bv[7] = f2bf(f1.w);
    af[ks] = bv;
  }

  const short* Wp = Wt + w3 * (H_ * C_);
  const float oscale = (w3 == 1) ? 0.05103103630798288f : 1.0f;  // 384^-0.5

  if (w3 == 2) {
    const int bb = row0 >> 12;
    const int tt = row0 & (T_ - 1);
    #pragma unroll
    for (int n = 0; n < 4; ++n) {
      bf16x8 wf[12];
      #pragma unroll
      for (int ks = 0; ks < 12; ++ks)
        wf[ks] = *(const bf16x8*)(Wp + (n * 16 + lrow) * C_ + ks * 32 + lgrp * 8);
      f32x4 acc = {0.f, 0.f, 0.f, 0.f};
      #pragma unroll
      for (int ks = 0; ks < 12; ++ks)
        acc = __builtin_amdgcn_mfma_f32_16x16x32_bf16(wf[ks], af[ks], acc, 0, 0, 0);
      #pragma unroll
      for (int r = 0; r < 4; ++r)
        vbT[(size_t)(bb * H_ + n * 16 + lgrp * 4 + r) * T_ + tt + lrow] = f2bf(acc[r]);
    }
  } else {
    short* outp = (w3 == 0) ? kb : qb;
    #pragma unroll
    for (int n = 0; n < 4; ++n) {
      bf16x8 wf[12];
      #pragma unroll
      for (int ks = 0; ks < 12; ++ks)
        wf[ks] = *(const bf16x8*)(Wp + (n * 16 + lrow) * C_ + ks * 32 + lgrp * 8);
      f32x4 acc = {0.f, 0.f, 0.f, 0.f};
      #pragma unroll
      for (int ks = 0; ks < 12; ++ks)
        acc = __builtin_amdgcn_mfma_f32_16x16x32_bf16(af[ks], wf[ks], acc, 0, 0, 0);
      #pragma unroll
      for (int r = 0; r < 4; ++r)
        outp[(size_t)(row0 + lgrp * 4 + r) * H_ + n * 16 + lrow] = f2bf(acc[r] * oscale);
    }
  }
}

// ---------------- Flash attention: swapped 32x32 QK^T, in-lane softmax -------
// One wave per (32-row q-tile, KV-split); ZERO LDS, no dependent shuffle trees.
// S^T = mfma(K, Q): lane holds 16 S-values of ONE q row (col=lane&31).
// kv(reg r, hi) = (r&3) + 8*(r>>2) + 4*hi. Cross-half exchange uses
// __shfl_xor(x, 32) (lane<->lane^32 — unambiguous semantics).
__global__ __launch_bounds__(256, 4) void attn_kernel(
    const short* __restrict__ qb, const short* __restrict__ kb,
    const short* __restrict__ vbT, float* __restrict__ po,
    float* __restrict__ pm, float* __restrict__ pl)
{
  const int tid = threadIdx.x;
  const int ws = tid >> 6;                        // wave id == KV-split id
  const int lane = tid & 63;
  const int q = lane & 31;                        // this lane's q row (= D col)
  const int hi = lane >> 5;

  // folded pairing: block t pairs long+short tasks -> equal per-CU load
  const int t = blockIdx.x >> 2;
  const int qtile = (t < 64) ? (127 - t) : (t - 64);
  const int b = blockIdx.x & 3;
  const int qrow0 = qtile * 32;

  const short* Q  = qb  + (size_t)b * T_ * H_;
  const short* K  = kb  + (size_t)b * T_ * H_;
  const short* Vt = vbT + (size_t)b * H_ * T_;

  // Q B-frags (col=lane&31=q, k(h) = s5*16 + hi*8 + j) — persistent
  bf16x8 qf[4];
  #pragma unroll
  for (int s5 = 0; s5 < 4; ++s5)
    qf[s5] = *(const bf16x8*)(Q + (size_t)(qrow0 + q) * H_ + s5 * 16 + hi * 8);

  f32x16 oa, ob;                                  // O^T: h = (r&3)+8*(r>>2)+4*hi (+32 for ob)
  #pragma unroll
  for (int r = 0; r < 16; ++r) { oa[r] = 0.f; ob[r] = 0.f; }
  float m = -INFINITY, l = 0.f;

  const int nch = qtile + 1;                      // 32-kv chunks (causal)

  for (int c4 = ws; c4 < nch; c4 += NSPL) {
    const int kv0 = c4 * 32;

    // ---- K A-frags (row=lane&31=kv, k(h)=s5*16+hi*8+j) ----
    bf16x8 kf[4];
    #pragma unroll
    for (int s5 = 0; s5 < 4; ++s5)
      kf[s5] = *(const bf16x8*)(K + (size_t)(kv0 + q) * H_ + s5 * 16 + hi * 8);

    // ---- S^T = K Q^T (q pre-scaled by 384^-0.5 in proj) ----
    f32x16 s;
    #pragma unroll
    for (int r = 0; r < 16; ++r) s[r] = 0.f;
    #pragma unroll
    for (int s5 = 0; s5 < 4; ++s5)
      s = __builtin_amdgcn_mfma_f32_32x32x16_bf16(kf[s5], qf[s5], s, 0, 0, 0);

    // ---- V^T A-frags for PV (issue early; latency hides under softmax) ----
    bf16x8 vf[4];                                 // [hh*2 + kstep]
    #pragma unroll
    for (int hh = 0; hh < 2; ++hh)
      #pragma unroll
      for (int ks = 0; ks < 2; ++ks)
        vf[hh * 2 + ks] = *(const bf16x8*)(
            Vt + (size_t)(hh * 32 + q) * T_ + kv0 + ks * 16 + hi * 8);

    // ---- causal mask (diagonal chunk only: kv0 == qrow0) ----
    if (kv0 + 32 > qrow0) {
      #pragma unroll
      for (int r = 0; r < 16; ++r) {
        const int kvloc = (r & 3) + 8 * (r >> 2) + 4 * hi;
        s[r] = (kv0 + kvloc > qrow0 + q) ? -INFINITY : s[r];
      }
    }

    // ---- in-lane max over 16, cross-half combine via shfl_xor(32) ----
    float t0 = fmaxf(s[0], s[1]),  t1 = fmaxf(s[2], s[3]);
    float t2 = fmaxf(s[4], s[5]),  t3 = fmaxf(s[6], s[7]);
    float t4 = fmaxf(s[8], s[9]),  t5 = fmaxf(s[10], s[11]);
    float t6 = fmaxf(s[12], s[13]), t7 = fmaxf(s[14], s[15]);
    float cm = fmaxf(fmaxf(fmaxf(t0, t1), fmaxf(t2, t3)),
                     fmaxf(fmaxf(t4, t5), fmaxf(t6, t7)));
    cm = fmaxf(cm, __shfl_xor(cm, 32, 64));
    const float nm = fmaxf(m, cm);
    const float alpha = __expf(m - nm);
    m = nm;

    // ---- p = exp(s - nm); in-lane sum + cross-half combine ----
    #pragma unroll
    for (int r = 0; r < 16; ++r) s[r] = __expf(s[r] - nm);
    float ss = ((s[0] + s[1]) + (s[2] + s[3])) + ((s[4] + s[5]) + (s[6] + s[7]))
             + ((s[8] + s[9]) + (s[10] + s[11])) + ((s[12] + s[13]) + (s[14] + s[15]));
    ss += __shfl_xor(ss, 32, 64);
    l = l * alpha + ss;
    #pragma unroll
    for (int r = 0; r < 16; ++r) { oa[r] *= alpha; ob[r] *= alpha; }

    // ---- P^T B-frags in-register via cvt_pk + shfl_xor(32) ----
    // own u_w = kv(4hi+2w, 4hi+2w+1), u_{2+w} = kv(8+4hi+2w, ...); pf0 needs
    // kv = hi*8 + {0..7}:  pf0 = hi ? {p2,p3,u2,u3} : {u0,u1,p0,p1}, p=partner.
    unsigned u0 = cvtpk(s[0], s[1]),   u1 = cvtpk(s[2], s[3]);
    unsigned u2 = cvtpk(s[4], s[5]),   u3 = cvtpk(s[6], s[7]);
    unsigned u4 = cvtpk(s[8], s[9]),   u5 = cvtpk(s[10], s[11]);
    unsigned u6 = cvtpk(s[12], s[13]), u7 = cvtpk(s[14], s[15]);
    const unsigned p0 = __shfl_xor((int)u0, 32, 64), p1 = __shfl_xor((int)u1, 32, 64);
    const unsigned p2 = __shfl_xor((int)u2, 32, 64), p3 = __shfl_xor((int)u3, 32, 64);
    const unsigned p4 = __shfl_xor((int)u4, 32, 64), p5 = __shfl_xor((int)u5, 32, 64);
    const unsigned p6 = __shfl_xor((int)u6, 32, 64), p7 = __shfl_xor((int)u7, 32, 64);
    const bf16x8 pf0 = __builtin_bit_cast(bf16x8,
        hi ? (u32x4){p2, p3, u2, u3} : (u32x4){u0, u1, p0, p1});
    const bf16x8 pf1 = __builtin_bit_cast(bf16x8,
        hi ? (u32x4){p6, p7, u6, u7} : (u32x4){u4, u5, p4, p5});

    // ---- O^T += V^T P^T ----
    oa = __builtin_amdgcn_mfma_f32_32x32x16_bf16(vf[0], pf0, oa, 0, 0, 0);
    oa = __builtin_amdgcn_mfma_f32_32x32x16_bf16(vf[1], pf1, oa, 0, 0, 0);
    ob = __builtin_amdgcn_mfma_f32_32x32x16_bf16(vf[2], pf0, ob, 0, 0, 0);
    ob = __builtin_amdgcn_mfma_f32_32x32x16_bf16(vf[3], pf1, ob, 0, 0, 0);
  }

  // ---- write partials: row = b*T + qrow0 + q, h from reg map ----
  float* prow = po + (size_t)ws * (B_ * T_ * H_)
              + ((size_t)b * T_ + qrow0 + q) * H_;
  #pragma unroll
  for (int g = 0; g < 4; ++g) {
    *(float4*)(prow + 8 * g + 4 * hi) =
        float4{oa[4 * g + 0], oa[4 * g + 1], oa[4 * g + 2], oa[4 * g + 3]};
    *(float4*)(prow + 32 + 8 * g + 4 * hi) =
        float4{ob[4 * g + 0], ob[4 * g + 1], ob[4 * g + 2], ob[4 * g + 3]};
  }
  if (hi == 0) {
    pm[(size_t)ws * (B_ * T_) + (size_t)b * T_ + qrow0 + q] = m;
    pl[(size_t)ws * (B_ * T_) + (size_t)b * T_ + qrow0 + q] = l;
  }
}

// ---------------- Merge the NSPL split partials ------------------------------
__global__ __launch_bounds__(256) void merge_kernel(
    const float* __restrict__ po, const float* __restrict__ pm,
    const float* __restrict__ pl, float* __restrict__ out)
{
  const int idx = blockIdx.x * 256 + threadIdx.x; // 0 .. B*T*H-1
  const int row = idx >> 6;
  float ms[NSPL], M = -INFINITY;
  #pragma unroll
  for (int s = 0; s < NSPL; ++s) {
    ms[s] = pm[(size_t)s * (B_ * T_) + row];
    M = fmaxf(M, ms[s]);
  }
  float num = 0.f, den = 0.f;
  #pragma unroll
  for (int s = 0; s < NSPL; ++s) {
    const float w = __expf(ms[s] - M);            // 0 for idle splits
    num += w * po[(size_t)s * (B_ * T_ * H_) + idx];
    den += w * pl[(size_t)s * (B_ * T_) + row];
  }
  out[idx] = num / den;
}

extern "C" void kernel_launch(void* const* d_in, const int* in_sizes, int n_in,
                              void* d_out, int out_size, void* d_ws, size_t ws_size,
                              hipStream_t stream) {
  const float* x  = (const float*)d_in[0];
  const float* Wk = (const float*)d_in[1];
  const float* Wq = (const float*)d_in[2];
  const float* Wv = (const float*)d_in[3];
  float* out = (float*)d_out;

  const size_t ntok = (size_t)B_ * T_;            // 16384
  char* ws = (char*)d_ws;
  short* qb  = (short*)ws;                                  // 2 MB
  short* kb  = qb + ntok * H_;                              // 2 MB
  short* vbT = kb + ntok * H_;                              // 2 MB
  short* Wt  = vbT + ntok * H_;                             // 144 KB
  float* po  = (float*)(ws + 3 * ntok * H_ * 2 + 3 * H_ * C_ * 2);  // 16 MB
  float* pm  = po + (size_t)NSPL * ntok * H_;               // 256 KB
  float* pl  = pm + (size_t)NSPL * ntok;                    // 256 KB

  wconv_kernel<<<dim3(96, 3), 256, 0, stream>>>(Wk, Wq, Wv, Wt);
  proj_mfma<<<dim3((int)(ntok / 64), 3), 256, 0, stream>>>(x, Wt, qb, kb, vbT);
  attn_kernel<<<128 * B_, 256, 0, stream>>>(qb, kb, vbT, po, pm, pl);
  merge_kernel<<<(int)(ntok * H_ / 256), 256, 0, stream>>>(po, pm, pl, out);
}